// Round 7
// baseline (21.230 us; speedup 1.0000x reference)
//
#include <hip/hip_runtime.h>
#include <math.h>
#include <stdint.h>

#define HF 64
#define WF 64
#define CC 512
#define NROI 256
#define NBINS 21   // 1 + 4 + 16

__device__ __forceinline__ float4 max4(float4 a, float4 b) {
    float4 r;
    r.x = fmaxf(a.x, b.x); r.y = fmaxf(a.y, b.y);
    r.z = fmaxf(a.z, b.z); r.w = fmaxf(a.w, b.w);
    return r;
}

__device__ __forceinline__ float4 ld4(const float* __restrict__ img, uint32_t byteoff) {
    return *(const float4*)((const char*)img + byteoff);
}

// Fused kernel: block = (roi, channel-quarter of 128 ch), 1024 threads = 16 waves.
//   wave wv -> fine bin (jy = wv>>2, jx = wv&3).
//   lanes: cl = lane&31 -> 4 channels (float4), half = lane>>5 -> pixel-column parity.
// Inner loop: BRANCH-FREE via clamped duplicate loads (min(idx,last) — duplicates
// are exact for max), rows x2 + cols x4 unroll -> 4 independent acc chains (MLP 4).
// 32-bit byte offsets + uniform img base -> saddr-form global_load_dwordx4.
// p2/p1 derived block-locally via LDS (exact; boundary arith bitwise = reference).
// XCD swizzle (proven r2-r5): bid&7 -> XCD, quarter q = (bid&7)>>1 -> XCD pair {2q,2q+1}.
__global__ __launch_bounds__(1024) void roi_pool_fused(
    const float* __restrict__ img,
    const float* __restrict__ rois,
    float* __restrict__ out)
{
    __shared__ float fineLds[4][4][128];   // [jy][jx][ch-in-quarter]
    __shared__ float p2Lds[2][2][128];     // [i2][j2][ch-in-quarter]

    const int bid  = blockIdx.x;                    // [0, 1024)
    const int q    = (bid & 7) >> 1;                // channel quarter
    const int roi  = ((bid >> 3) << 1) | (bid & 1); // [0, 256) bijective
    const int tid  = threadIdx.x;
    const int wv   = tid >> 6;                      // wave id = fine bin
    const int jy   = wv >> 2;                       // y fine-bin (H axis)
    const int jx   = wv & 3;                        // x fine-bin (W axis)
    const int lane = tid & 63;
    const int half = lane >> 5;                     // pixel-column parity
    const int cl   = lane & 31;                     // channel lane
    const int c0   = q * 128 + cl * 4;

    const float x = rois[roi * 4 + 0];
    const float y = rois[roi * 4 + 1];
    const float w = rois[roi * 4 + 2];
    const float h = rois[roi * 4 + 3];

    // Reference quirk: x-boundaries (W axis) use col_len = h/p; y-boundaries use w/p.
    const float clh = h * 0.25f;   // exact
    const float clw = w * 0.25f;   // exact

    const int x1 = (int)rintf(__fadd_rn(x, __fmul_rn((float)jx,       clh)));
    const int x2 = (int)rintf(__fadd_rn(x, __fmul_rn((float)(jx + 1), clh)));
    const int y1 = (int)rintf(__fadd_rn(y, __fmul_rn((float)jy,       clw)));
    const int y2 = (int)rintf(__fadd_rn(y, __fmul_rn((float)(jy + 1), clw)));

    const int ylast = y2 - 1;
    const int xlast = x2 - 1;

    float4 acc0, acc1, acc2, acc3;
    acc0.x = -INFINITY; acc0.y = -INFINITY; acc0.z = -INFINITY; acc0.w = -INFINITY;
    acc1 = acc0; acc2 = acc0; acc3 = acc0;

    const uint32_t ROWB = WF * CC * 4;   // 131072
    const uint32_t PXB  = CC * 4;        // 2048
    const uint32_t cb   = (uint32_t)c0 * 4;

    for (int hh = y1; hh < y2; hh += 2) {
        const int h1 = min(hh + 1, ylast);
        const uint32_t ro0 = cb + (uint32_t)hh * ROWB;
        const uint32_t ro1 = cb + (uint32_t)h1 * ROWB;
        for (int cc = x1; cc < x2; cc += 4) {
            const uint32_t w0 = (uint32_t)min(cc + half,     xlast) * PXB;
            const uint32_t w1 = (uint32_t)min(cc + 2 + half, xlast) * PXB;
            const float4 v0 = ld4(img, ro0 + w0);
            const float4 v1 = ld4(img, ro1 + w0);
            const float4 v2 = ld4(img, ro0 + w1);
            const float4 v3 = ld4(img, ro1 + w1);
            acc0 = max4(acc0, v0);
            acc1 = max4(acc1, v1);
            acc2 = max4(acc2, v2);
            acc3 = max4(acc3, v3);
        }
    }
    float4 acc = max4(max4(acc0, acc1), max4(acc2, acc3));

    // combine the two pixel-parity halves (same channels, disjoint pixel sets)
    acc.x = fmaxf(acc.x, __shfl_xor(acc.x, 32));
    acc.y = fmaxf(acc.y, __shfl_xor(acc.y, 32));
    acc.z = fmaxf(acc.z, __shfl_xor(acc.z, 32));
    acc.w = fmaxf(acc.w, __shfl_xor(acc.w, 32));

    float* outr = out + (size_t)roi * (NBINS * CC) + c0;

    if (half == 0) {
        *(float4*)(outr + (size_t)(5 + jx * 4 + jy) * CC) = acc;
        *(float4*)(&fineLds[jy][jx][cl * 4]) = acc;
    }
    __syncthreads();

    // p2: waves 0..3 -> coarse bin (i2 = wv>>1, j2 = wv&1)
    if (wv < 4 && half == 0) {
        const int i2 = wv >> 1;
        const int j2 = wv & 1;
        const float4 f00 = *(const float4*)(&fineLds[2*j2  ][2*i2  ][cl * 4]);
        const float4 f01 = *(const float4*)(&fineLds[2*j2  ][2*i2+1][cl * 4]);
        const float4 f10 = *(const float4*)(&fineLds[2*j2+1][2*i2  ][cl * 4]);
        const float4 f11 = *(const float4*)(&fineLds[2*j2+1][2*i2+1][cl * 4]);
        const float4 a = max4(max4(f00, f01), max4(f10, f11));
        *(float4*)(outr + (size_t)(1 + i2 * 2 + j2) * CC) = a;
        *(float4*)(&p2Lds[i2][j2][cl * 4]) = a;
    }
    __syncthreads();

    // p1: wave 0
    if (wv == 0 && half == 0) {
        const float4 a00 = *(const float4*)(&p2Lds[0][0][cl * 4]);
        const float4 a01 = *(const float4*)(&p2Lds[0][1][cl * 4]);
        const float4 a10 = *(const float4*)(&p2Lds[1][0][cl * 4]);
        const float4 a11 = *(const float4*)(&p2Lds[1][1][cl * 4]);
        *(float4*)(outr) = max4(max4(a00, a01), max4(a10, a11));
    }
}

extern "C" void kernel_launch(void* const* d_in, const int* in_sizes, int n_in,
                              void* d_out, int out_size, void* d_ws, size_t ws_size,
                              hipStream_t stream) {
    const float* img  = (const float*)d_in[0];   // (1,64,64,512) fp32
    const float* rois = (const float*)d_in[1];   // (1,256,4) fp32
    float* out = (float*)d_out;                  // (1,256,21*512) fp32

    dim3 grid(NROI * 4);     // (roi, quarter) = 1024 blocks
    dim3 block(1024);        // 16 waves = 16 fine bins
    roi_pool_fused<<<grid, block, 0, stream>>>(img, rois, out);
}